// Round 9
// baseline (206.410 us; speedup 1.0000x reference)
//
#include <hip/hip_runtime.h>

// Problem: B=4, S=2048, H=16, D=64, E=1024. Inputs fp32, output fp32.
// out = proj( attention( cos(x+theta) ) )  with Q==K==V per head.
//
// Round 9: proj switched to m97 structure (global_load_lds width=16, unpadded
// LDS, 2-barrier K-loop); attn K/V staging register-prefetched (loads for
// kt+1 issued after the compute barrier, hidden under MFMA/softmax).
// ws: [0,16M) qkv  [16M,32M) qkvT  [32M,48M) aout  [48M,50M) Wbf.

#define B_  4
#define S_  2048
#define H_  16
#define D_  64
#define E_  1024
// exp(s/8) = exp2(s * log2(e)/8); folded into Q fragments
#define EXP2_SCALE 0.18033688011112043f

typedef unsigned short u16;
typedef unsigned int u32;
typedef __attribute__((ext_vector_type(8))) short short8;
typedef __attribute__((ext_vector_type(4))) float floatx4;

static __device__ __forceinline__ float bf2f(u16 v) {
    return __uint_as_float(((unsigned)v) << 16);
}
static __device__ __forceinline__ u16 f2bf(float f) {
    unsigned u = __float_as_uint(f);
    return (u16)((u + 0x7FFFu + ((u >> 16) & 1u)) >> 16);
}
// pack bf16(lo),bf16(hi) from two f32 by truncation: 1 v_perm_b32
static __device__ __forceinline__ u32 pack_bf16_trunc(float lo, float hi) {
    return __builtin_amdgcn_perm(__float_as_uint(hi), __float_as_uint(lo), 0x07060302u);
}
// unpack-scale-repack a short8 of bf16 by EXP2_SCALE (one-time, RNE)
static __device__ __forceinline__ short8 scale8(short8 v) {
    short8 o;
#pragma unroll
    for (int i = 0; i < 8; i++)
        o[i] = (short)f2bf(bf2f((u16)v[i]) * EXP2_SCALE);
    return o;
}

// async global->LDS 16B copy (CK-style address-space casts).
// LDS dst semantics: wave-uniform base + lane*16 (m104/m108) — callers pass a
// wave-uniform lds base; lane's global ptr selects its own 16B chunk.
static __device__ __forceinline__ void gload_lds16(const u16* g, u16* l) {
    __builtin_amdgcn_global_load_lds(
        (const __attribute__((address_space(1))) u32*)g,
        (__attribute__((address_space(3))) u32*)l, 16, 0, 0);
}

// ---------------------------------------------------------------------------
// Kernel 1 (fused prep):
//  blocks [0,2048):   qkv[bh][s][d] = cos(x+theta) bf16, qkvT = transpose
//  blocks [2048,3072): Wbf = bf16(W)
// ---------------------------------------------------------------------------
__global__ __launch_bounds__(256) void prep_kernel(const float* __restrict__ x,
                                                   const float* __restrict__ theta,
                                                   const float* __restrict__ W,
                                                   u16* __restrict__ qkv,
                                                   u16* __restrict__ qkvT,
                                                   u16* __restrict__ Wb) {
    __shared__ __align__(16) u16 TQ[64][72];
    int blk = blockIdx.x;
    int tid = threadIdx.x;
    if (blk >= 2048) {  // wconv part
        int i = ((blk - 2048) * 256 + tid) * 4;
        float4 w = *(const float4*)(W + i);
        ushort4 o;
        o.x = f2bf(w.x); o.y = f2bf(w.y); o.z = f2bf(w.z); o.w = f2bf(w.w);
        *(ushort4*)(Wb + i) = o;
        return;
    }
    int stile = blk & 31;
    int bh    = blk >> 5;
    int b     = bh >> 4;
    int h     = bh & 15;
    int i     = tid >> 2;
    int d0    = (tid & 3) << 4;
    int s0    = stile << 6;
    int s     = s0 + i;

    const float* xp = x + ((size_t)(b * S_ + s)) * E_ + h * D_ + d0;
    const float* tp = theta + h * D_ + d0;

    u16 ov[16];
#pragma unroll
    for (int j = 0; j < 16; j += 4) {
        float4 xv = *(const float4*)(xp + j);
        float4 tv = *(const float4*)(tp + j);
        ov[j]     = f2bf(__cosf(xv.x + tv.x));
        ov[j + 1] = f2bf(__cosf(xv.y + tv.y));
        ov[j + 2] = f2bf(__cosf(xv.z + tv.z));
        ov[j + 3] = f2bf(__cosf(xv.w + tv.w));
    }

    u16* qp = qkv + ((size_t)bh * S_ + s) * D_ + d0;
    *(uint4*)qp       = *(uint4*)&ov[0];
    *(uint4*)(qp + 8) = *(uint4*)&ov[8];

#pragma unroll
    for (int j = 0; j < 16; j++) TQ[d0 + j][i] = ov[j];
    __syncthreads();

    int d  = tid >> 2;
    int j0 = (tid & 3) << 4;
    u16 tmp[16];
#pragma unroll
    for (int j = 0; j < 16; j++) tmp[j] = TQ[d][j0 + j];
    u16* qtp = qkvT + ((size_t)bh * D_ + d) * S_ + s0 + j0;
    *(uint4*)qtp       = *(uint4*)&tmp[0];
    *(uint4*)(qtp + 8) = *(uint4*)&tmp[8];
}

// ---------------------------------------------------------------------------
// Kernel 2: flash attention per (bh, 128-q-tile), S^T formulation.
// 4 waves; wave w owns q rows [w*32,w*32+32) as rf=0,1 (16 q each).
// K/V tiles register-prefetched one iteration ahead.
// ---------------------------------------------------------------------------
__global__ __launch_bounds__(256, 4) void attn_kernel(const u16* __restrict__ qkv,
                                                      const u16* __restrict__ qkvT,
                                                      u16* __restrict__ aout) {
    int blk  = blockIdx.x;
    int qt   = blk & 15;
    int bh   = blk >> 4;
    int b    = bh >> 4;
    int h    = bh & 15;
    int tid  = threadIdx.x;
    int wave = tid >> 6;
    int lane = tid & 63;
    int lq   = lane & 15;
    int lg   = lane >> 4;
    int r    = tid >> 2;        // staging row 0..63
    int c0   = (tid & 3) << 4;  // staging col base

    __shared__ __align__(16) u16 Kt[64][72];      // K tile [key][d]
    __shared__ __align__(16) u16 Vt[64][72];      // V^T tile [d][key]
    __shared__ __align__(16) u16 Pb[4][32][72];   // per-wave P [q][key]

    const u16* base  = qkv  + (size_t)bh * S_ * D_;
    const u16* baseT = qkvT + (size_t)bh * D_ * S_;
    int s0 = qt * 128;

    // Q B-frags (pre-scaled by EXP2_SCALE), loaded once. B[k=d][n=q=lq]
    short8 bq[2][2];
#pragma unroll
    for (int rf = 0; rf < 2; rf++) {
        const u16* qrow = base + (size_t)(s0 + wave * 32 + rf * 16 + lq) * D_ + lg * 8;
        bq[rf][0] = scale8(*(const short8*)qrow);
        bq[rf][1] = scale8(*(const short8*)(qrow + 32));
    }

    floatx4 oacc[2][4] = {{{0,0,0,0},{0,0,0,0},{0,0,0,0},{0,0,0,0}},
                          {{0,0,0,0},{0,0,0,0},{0,0,0,0},{0,0,0,0}}};
    float lsum[2] = {0.f, 0.f};

    // prefetch tile 0 into registers
    uint4 k0, k1, v0, v1;
    {
        const u16* p = base + (size_t)r * D_ + c0;
        k0 = *(const uint4*)p;
        k1 = *(const uint4*)(p + 8);
        const u16* p2 = baseT + (size_t)r * S_ + c0;
        v0 = *(const uint4*)p2;
        v1 = *(const uint4*)(p2 + 8);
    }

    for (int kt = 0; kt < S_ / 64; kt++) {
        __syncthreads();   // prev iteration's Kt/Vt reads complete
        *(uint4*)&Kt[r][c0]     = k0;
        *(uint4*)&Kt[r][c0 + 8] = k1;
        *(uint4*)&Vt[r][c0]     = v0;
        *(uint4*)&Vt[r][c0 + 8] = v1;
        __syncthreads();

        // issue next tile's loads now — hidden under this iteration's compute
        if (kt + 1 < S_ / 64) {
            const u16* p = base + (size_t)((kt + 1) * 64 + r) * D_ + c0;
            k0 = *(const uint4*)p;
            k1 = *(const uint4*)(p + 8);
            const u16* p2 = baseT + (size_t)r * S_ + (kt + 1) * 64 + c0;
            v0 = *(const uint4*)p2;
            v1 = *(const uint4*)(p2 + 8);
        }

        // S^T tiles: A = K-frag, B = bq. sc[rf][t][rr]: key=16t+4lg+rr, q=lq
        floatx4 sc[2][4];
#pragma unroll
        for (int t = 0; t < 4; t++) {
            short8 a0 = *(short8*)&Kt[t * 16 + lq][lg * 8];
            short8 a1 = *(short8*)&Kt[t * 16 + lq][32 + lg * 8];
#pragma unroll
            for (int rf = 0; rf < 2; rf++) {
                floatx4 acc = {0, 0, 0, 0};
                acc = __builtin_amdgcn_mfma_f32_16x16x32_bf16(a0, bq[rf][0], acc, 0, 0, 0);
                sc[rf][t] = __builtin_amdgcn_mfma_f32_16x16x32_bf16(a1, bq[rf][1], acc, 0, 0, 0);
            }
        }

        // p = exp2(sc); lane-scalar lsum; pack pairs; b64 store to Pb[q][key]
#pragma unroll
        for (int rf = 0; rf < 2; rf++) {
#pragma unroll
            for (int t = 0; t < 4; t++) {
                float p0 = __builtin_amdgcn_exp2f(sc[rf][t][0]);
                float p1 = __builtin_amdgcn_exp2f(sc[rf][t][1]);
                float p2 = __builtin_amdgcn_exp2f(sc[rf][t][2]);
                float p3 = __builtin_amdgcn_exp2f(sc[rf][t][3]);
                lsum[rf] += (p0 + p1) + (p2 + p3);
                uint2 w;
                w.x = pack_bf16_trunc(p0, p1);
                w.y = pack_bf16_trunc(p2, p3);
                *(uint2*)&Pb[wave][rf * 16 + lq][t * 16 + lg * 4] = w;
            }
        }

        // per-wave DS in-order: drain writes before dependent reads
        asm volatile("s_waitcnt lgkmcnt(0)" ::: "memory");

        // O^T += V^T · P^T
        short8 bp[2][2];
#pragma unroll
        for (int rf = 0; rf < 2; rf++) {
            bp[rf][0] = *(short8*)&Pb[wave][rf * 16 + lq][lg * 8];
            bp[rf][1] = *(short8*)&Pb[wave][rf * 16 + lq][32 + lg * 8];
        }
#pragma unroll
        for (int t = 0; t < 4; t++) {
            short8 av0 = *(short8*)&Vt[t * 16 + lq][lg * 8];
            short8 av1 = *(short8*)&Vt[t * 16 + lq][32 + lg * 8];
#pragma unroll
            for (int rf = 0; rf < 2; rf++) {
                oacc[rf][t] = __builtin_amdgcn_mfma_f32_16x16x32_bf16(av0, bp[rf][0], oacc[rf][t], 0, 0, 0);
                oacc[rf][t] = __builtin_amdgcn_mfma_f32_16x16x32_bf16(av1, bp[rf][1], oacc[rf][t], 0, 0, 0);
            }
        }
    }

    // reduce lsum across the 4 lane-quads holding the same q
#pragma unroll
    for (int rf = 0; rf < 2; rf++) {
        lsum[rf] += __shfl_xor(lsum[rf], 16);
        lsum[rf] += __shfl_xor(lsum[rf], 32);
    }
    // epilogue: O^T lane (q=lq, d=16t+4lg+rr) -> aout[b][q][h*64+d]
#pragma unroll
    for (int rf = 0; rf < 2; rf++) {
        float inv = 1.0f / fmaxf(lsum[rf], 1e-20f);
        int srow = s0 + wave * 32 + rf * 16 + lq;
        u16* arow = aout + ((size_t)(b * S_ + srow)) * E_ + h * D_;
#pragma unroll
        for (int t = 0; t < 4; t++)
#pragma unroll
            for (int rr = 0; rr < 4; rr++)
                arow[t * 16 + lg * 4 + rr] = f2bf(oacc[rf][t][rr] * inv);
    }
}

// ---------------------------------------------------------------------------
// Kernel 3: out[8192][1024] = AO * Wb^T + bias (fp32 out). Wb bf16 [n][k].
// m97 structure: 128x128 tile, BK=64, UNPADDED [128][64] LDS, staging via
// global_load_lds dwordx4, 2 barriers per K-iter. 4 waves 2x2, 4x4 accs.
// ---------------------------------------------------------------------------
__global__ __launch_bounds__(256) void proj_kernel(const u16* __restrict__ A,
                                                   const u16* __restrict__ Wb,
                                                   const float* __restrict__ bias,
                                                   float* __restrict__ out) {
    int m0   = blockIdx.x * 128;
    int n0   = blockIdx.y * 128;
    int tid  = threadIdx.x;
    int wave = tid >> 6;
    int wm   = wave >> 1;
    int wn   = wave & 1;
    int lane = tid & 63;
    int lq   = lane & 15;
    int lg   = lane >> 4;

    __shared__ __align__(16) u16 As[128 * 64];
    __shared__ __align__(16) u16 Bs[128 * 64];

    floatx4 acc[4][4];
#pragma unroll
    for (int i = 0; i < 4; i++)
#pragma unroll
        for (int j = 0; j < 4; j++) acc[i][j] = (floatx4){0, 0, 0, 0};

    for (int kc = 0; kc < E_; kc += 64) {
        __syncthreads();
        // async stage: 1024 16B-chunks per array; chunk ci -> row=ci>>3, col8=ci&7
#pragma unroll
        for (int c = 0; c < 4; c++) {
            int cb = (wave * 4 + c) * 64;        // wave-uniform chunk base
            int ci = cb + lane;
            int row = ci >> 3, col8 = ci & 7;
            gload_lds16(A  + (size_t)(m0 + row) * E_ + kc + col8 * 8, &As[(size_t)cb * 8]);
            gload_lds16(Wb + (size_t)(n0 + row) * E_ + kc + col8 * 8, &Bs[(size_t)cb * 8]);
        }
        asm volatile("s_waitcnt vmcnt(0)" ::: "memory");
        __syncthreads();

#pragma unroll
        for (int c = 0; c < 2; c++) {
            short8 af[4], bf[4];
#pragma unroll
            for (int i = 0; i < 4; i++)
                af[i] = *(short8*)&As[(wm * 64 + i * 16 + lq) * 64 + c * 32 + lg * 8];
#pragma unroll
            for (int j = 0; j < 4; j++)
                bf[j] = *(short8*)&Bs[(wn * 64 + j * 16 + lq) * 64 + c * 32 + lg * 8];
#pragma unroll
            for (int i = 0; i < 4; i++)
#pragma unroll
                for (int j = 0; j < 4; j++)
                    acc[i][j] = __builtin_amdgcn_mfma_f32_16x16x32_bf16(af[i], bf[j], acc[i][j], 0, 0, 0);
        }
    }

#pragma unroll
    for (int j = 0; j < 4; j++) {
        int nidx = n0 + wn * 64 + j * 16 + lq;
        float bv = bias[nidx];
#pragma unroll
        for (int i = 0; i < 4; i++) {
#pragma unroll
            for (int rr = 0; rr < 4; rr++) {
                int row = m0 + wm * 64 + i * 16 + lg * 4 + rr;
                out[(size_t)row * E_ + nidx] = acc[i][j][rr] + bv;
            }
        }
    }
}

// ---------------------------------------------------------------------------
extern "C" void kernel_launch(void* const* d_in, const int* in_sizes, int n_in,
                              void* d_out, int out_size, void* d_ws, size_t ws_size,
                              hipStream_t stream) {
    const float* x     = (const float*)d_in[0];
    const float* theta = (const float*)d_in[1];
    const float* w_out = (const float*)d_in[2];
    const float* b_out = (const float*)d_in[3];
    float* out = (float*)d_out;

    char* ws = (char*)d_ws;
    const size_t QKV_BYTES = (size_t)B_ * H_ * S_ * D_ * sizeof(u16);  // 16 MiB
    u16* qkv  = (u16*)ws;
    u16* qkvT = (u16*)(ws + QKV_BYTES);
    u16* aout = (u16*)(ws + 2 * QKV_BYTES);
    u16* wbf  = (u16*)(ws + 3 * QKV_BYTES);   // [48M,50M): own region (ws>=50M proven R8)

    prep_kernel<<<3072, 256, 0, stream>>>(x, theta, w_out, qkv, qkvT, wbf);
    attn_kernel<<<(B_ * H_) * (S_ / 128), 256, 0, stream>>>(qkv, qkvT, aout);
    dim3 pg(B_ * S_ / 128, E_ / 128);
    proj_kernel<<<pg, 256, 0, stream>>>(aout, wbf, b_out, out);
}